// Round 16
// baseline (307.027 us; speedup 1.0000x reference)
//
#include <hip/hip_runtime.h>
#include <hip/hip_bf16.h>

#define NN 4096
#define DD 128
#define NS 75

#define NT64 (NN / 64)                      // 64
#define GRID_TRI (NT64 * (NT64 + 1) / 2)    // 2080 upper-tri 64x64 tiles
#define GRID_FULL (NT64 * NT64)             // 4096

typedef float v2f __attribute__((ext_vector_type(2)));
typedef float f32x4 __attribute__((ext_vector_type(4)));
typedef short bf16x8 __attribute__((ext_vector_type(8)));

__device__ __forceinline__ float fexp2(float v) { return __builtin_amdgcn_exp2f(v); }

// DPP lane-shift add (register-file crossing, no LDS latency).
template <int CTRL>
__device__ __forceinline__ float dpp_add(float x) {
    int y = __builtin_amdgcn_update_dpp(0, __float_as_int(x), CTRL, 0xf, 0xf, true);
    return x + __int_as_float(y);
}
__device__ __forceinline__ float wave_sum(float x) {   // result in lane 63
    x = dpp_add<0x111>(x);
    x = dpp_add<0x112>(x);
    x = dpp_add<0x114>(x);
    x = dpp_add<0x118>(x);
    x = dpp_add<0x142>(x);
    x = dpp_add<0x143>(x);
    return x;
}

// linear index -> (bi, bj), bi <= bj, row-major over upper triangle
__device__ __forceinline__ void tri_decode(int t, int nb, int& bi, int& bj) {
    int b = 0, rem = t;
    while (rem >= nb - b) { rem -= nb - b; ++b; }   // uniform -> scalar
    bi = b; bj = b + rem;
}

// f32 -> bf16 hi (truncate) + bf16 lo (truncate of exact residual)
__device__ __forceinline__ void cvt_split(const float4& v0, const float4& v1,
                                          bf16x8& hi, bf16x8& lo) {
    float f[8] = {v0.x, v0.y, v0.z, v0.w, v1.x, v1.y, v1.z, v1.w};
#pragma unroll
    for (int j = 0; j < 8; ++j) {
        unsigned b = __float_as_uint(f[j]);
        hi[j] = (short)(b >> 16);
        float l = f[j] - __uint_as_float(b & 0xFFFF0000u);
        lo[j] = (short)(__float_as_uint(l) >> 16);
    }
}

// Recompute one 64x64 d2 tile in registers via split-bf16 MFMA.
// 4 waves: wave wid owns slab rows wid*16..+15. Thread's 16 values:
// dv[ct][v] = d2(row = tr*64 + wid*16 + (l>>4)*4 + v,
//                col = tc*64 + ct*16 + (l&15))
// Bitwise-identical to R13-15's k_d2 (same MFMA sequence: hh, hl, lh per kc).
__device__ __forceinline__ void d2_tile(const float* __restrict__ x,
                                        const float* __restrict__ sq,
                                        int tr, int tc, float dv[4][4]) {
    const int l = threadIdx.x & 63, wid = threadIdx.x >> 6;
    const int lr = l & 15;
    const int lkb = (l >> 4) * 8;
    const int arow = tr * 64 + wid * 16 + lr;

    f32x4 acc[4];
#pragma unroll
    for (int ct = 0; ct < 4; ++ct) acc[ct] = (f32x4){0.f, 0.f, 0.f, 0.f};

#pragma unroll 1
    for (int kc = 0; kc < 4; ++kc) {
        const int k0 = kc * 32 + lkb;
        bf16x8 ah, al;
        {
            const float* pa = x + (size_t)arow * DD + k0;
            float4 a0 = *(const float4*)pa;
            float4 a1 = *(const float4*)(pa + 4);
            cvt_split(a0, a1, ah, al);
        }
        bf16x8 bh[4], bl[4];
#pragma unroll
        for (int ct = 0; ct < 4; ++ct) {
            const float* pb = x + (size_t)(tc * 64 + ct * 16 + lr) * DD + k0;
            float4 b0 = *(const float4*)pb;
            float4 b1 = *(const float4*)(pb + 4);
            cvt_split(b0, b1, bh[ct], bl[ct]);
        }
#pragma unroll
        for (int ct = 0; ct < 4; ++ct) {
            acc[ct] = __builtin_amdgcn_mfma_f32_16x16x32_bf16(ah, bh[ct], acc[ct], 0, 0, 0);
            acc[ct] = __builtin_amdgcn_mfma_f32_16x16x32_bf16(ah, bl[ct], acc[ct], 0, 0, 0);
            acc[ct] = __builtin_amdgcn_mfma_f32_16x16x32_bf16(al, bh[ct], acc[ct], 0, 0, 0);
        }
    }

    const int rb = tr * 64 + wid * 16 + (l >> 4) * 4;
    float4 s4 = *(const float4*)(sq + rb);
    float sr[4] = {s4.x, s4.y, s4.z, s4.w};
#pragma unroll
    for (int ct = 0; ct < 4; ++ct) {
        float sc = sq[tc * 64 + ct * 16 + lr];
#pragma unroll
        for (int v = 0; v < 4; ++v)
            dv[ct][v] = fmaxf(sr[v] + sc - 2.f * acc[ct][v], 0.f);
    }
}

// Coarse argmax over slots 0..24 -> refine window base (deterministic).
__device__ __forceinline__ int coarse_window(const double* KL, const double* KK) {
    double best = -1.0;
    int bk = 0;
    for (int k = 0; k < 25; ++k) {
        double loss = KL[k] / sqrt(KK[k]);
        if (loss > best) { best = loss; bk = k; }   // strict > = first max
    }
    int wv = 3 * bk - 2;
    if (wv < 0) wv = 0;
    if (wv > NS - 5) wv = NS - 5;
    return wv;
}

// ---------------- ws layout (bytes) ----------------
#define WS_DSUM 0                      // double
#define WS_NZC  8                      // unsigned long long
#define WS_KL   16                     // double[32] (0..24 coarse, 25..29 refine)
#define WS_KK   (16 + 256)             // double[32]
#define WS_SQ   (16 + 512)             // float[NN]
#define WS_CSIG (WS_SQ + 4 * NN)       // float[NS]

__global__ void k_rowsq(const float* __restrict__ x, float* __restrict__ sq,
                        double* __restrict__ dsum, unsigned long long* __restrict__ nzc) {
    int tid = blockIdx.x * blockDim.x + threadIdx.x;
    if (tid == 0) { *dsum = 0.0; *nzc = 0ull; }
    if (tid < NN) {
        const float4* row = (const float4*)(x + (size_t)tid * DD);
        float s = 0.f;
#pragma unroll
        for (int i = 0; i < DD / 4; ++i) {
            float4 v = row[i];
            s += v.x * v.x + v.y * v.y + v.z * v.z + v.w * v.w;
        }
        sq[tid] = s;
    }
}

// Mean distance: recompute d2 per upper-tri tile (no store), sum sqrt + count.
__launch_bounds__(256)
__global__ void k_mean(const float* __restrict__ x, const float* __restrict__ sq,
                       double* __restrict__ dsum, unsigned long long* __restrict__ nzc) {
    __shared__ double red_d[4];
    __shared__ int red_n[4];
    int ti, tj;
    tri_decode(blockIdx.x, NT64, ti, tj);

    float dv[4][4];
    d2_tile(x, sq, ti, tj, dv);

    float myd = 0.f;
    int myn = 0;
#pragma unroll
    for (int ct = 0; ct < 4; ++ct)
#pragma unroll
        for (int v = 0; v < 4; ++v) {
            float d = dv[ct][v];
            if (d > 0.f) { myd += sqrtf(d); ++myn; }
        }

    const int w = (ti == tj) ? 1 : 2;
    float sd = wave_sum(myd);
    float sn = wave_sum((float)myn);
    const int wid = threadIdx.x >> 6;
    if ((threadIdx.x & 63) == 63) { red_d[wid] = (double)sd; red_n[wid] = (int)sn; }
    __syncthreads();
    if (threadIdx.x == 0) {
        double td = red_d[0] + red_d[1] + red_d[2] + red_d[3];
        int tn = red_n[0] + red_n[1] + red_n[2] + red_n[3];
        atomicAdd(dsum, td * (double)w);
        atomicAdd(nzc, (unsigned long long)(tn * w));
    }
}

__global__ void k_sigmas(const double* __restrict__ dsum, const unsigned long long* __restrict__ nzc,
                         float* __restrict__ csig, double* __restrict__ KL, double* __restrict__ KK) {
    int t = threadIdx.x;
    float mean = (float)(*dsum / (double)(*nzc));
    float lo = 0.1f * mean;
    float hi = 10.0f * mean;
    float step = (hi - lo) / (float)NS;
    if (t < NS) {
        float s = lo + step * (float)t;
        csig[t] = (float)(1.4426950408889634 / ((double)s * (double)s));
    }
    if (t < 32) { KL[t] = 0.0; KK[t] = 0.0; }
}

// Load the thread's 16 lk values matching d2_tile's (ct,v) coordinates.
__device__ __forceinline__ void load_lk(const float* __restrict__ lkp,
                                        int tr, int tc, float lv[4][4]) {
    const int l = threadIdx.x & 63, wid = threadIdx.x >> 6;
    const int rb = tr * 64 + wid * 16 + (l >> 4) * 4;
    const int cb = tc * 64 + (l & 15);
#pragma unroll
    for (int ct = 0; ct < 4; ++ct)
#pragma unroll
        for (int v = 0; v < 4; ++v)
            lv[ct][v] = lkp[(size_t)(rb + v) * NN + cb + ct * 16];
}

// One coarse sigma-phase: CH stride-3 sigmas starting at index S0.
template <int CH, int S0>
__device__ __forceinline__ void coarse_phase(const v2f nd[8], const v2f ll[8],
                                             const float* __restrict__ csig,
                                             double part[][50], int wave, int lane) {
    float c[CH];
#pragma unroll
    for (int q = 0; q < CH; ++q)   // SGPR residency
        c[q] = __int_as_float(__builtin_amdgcn_readfirstlane(
                   __float_as_int(csig[3 * (S0 + q)])));
    v2f akl[CH], akk[CH];
#pragma unroll
    for (int q = 0; q < CH; ++q) { akl[q] = (v2f){0.f, 0.f}; akk[q] = (v2f){0.f, 0.f}; }
#pragma unroll
    for (int e = 0; e < 8; ++e) {
        v2f ndv = nd[e], L = ll[e];
#pragma unroll
        for (int q = 0; q < CH; ++q) {
            v2f arg = ndv * c[q];                               // v_pk_mul_f32
            v2f K = {fexp2(arg.x), fexp2(arg.y)};               // 2x v_exp_f32
            akl[q] = __builtin_elementwise_fma(K, L, akl[q]);   // v_pk_fma_f32
            akk[q] = __builtin_elementwise_fma(K, K, akk[q]);
        }
    }
#pragma unroll
    for (int q = 0; q < CH; ++q) {
        float v1 = wave_sum(akl[q].x + akl[q].y);
        float v2 = wave_sum(akk[q].x + akk[q].y);
        if (lane == 63) {
            part[wave][S0 + q]      = (double)v1;
            part[wave][25 + S0 + q] = (double)v2;
        }
    }
}

// Coarse sweep: recompute d2 (MFMA), load lk, 25 stride-3 sigmas over
// register-resident data; per-tile weight 2 off-diag.
__launch_bounds__(256, 3)
__global__ void k_sweep_coarse(const float* __restrict__ x, const float* __restrict__ sq,
                               const float* __restrict__ lkp, const float* __restrict__ csig,
                               double* __restrict__ KL, double* __restrict__ KK) {
    int ti, tj;
    tri_decode(blockIdx.x, NT64, ti, tj);
    const double w = (ti == tj) ? 1.0 : 2.0;

    float dv[4][4];
    d2_tile(x, sq, ti, tj, dv);
    float lv[4][4];
    load_lk(lkp, ti, tj, lv);

    v2f nd[8], ll[8];
#pragma unroll
    for (int ct = 0; ct < 4; ++ct) {
        nd[ct * 2 + 0] = (v2f){-dv[ct][0], -dv[ct][1]};
        nd[ct * 2 + 1] = (v2f){-dv[ct][2], -dv[ct][3]};
        ll[ct * 2 + 0] = (v2f){lv[ct][0], lv[ct][1]};
        ll[ct * 2 + 1] = (v2f){lv[ct][2], lv[ct][3]};
    }

    __shared__ double part[4][50];
    const int lane = threadIdx.x & 63, wave = threadIdx.x >> 6;

    coarse_phase<13, 0>(nd, ll, csig, part, wave, lane);
    coarse_phase<12, 13>(nd, ll, csig, part, wave, lane);

    __syncthreads();
    const int t = threadIdx.x;
    if (t < 50) {
        double v = w * (part[0][t] + part[1][t] + part[2][t] + part[3][t]);
        if (t < 25) atomicAdd(&KL[t], v);
        else        atomicAdd(&KK[t - 25], v);
    }
}

// Refine sweep: window from coarse sums (recomputed per block), 5 stride-1
// sigmas into slots 25..29.
__launch_bounds__(256, 3)
__global__ void k_sweep_refine(const float* __restrict__ x, const float* __restrict__ sq,
                               const float* __restrict__ lkp, const float* __restrict__ csig,
                               double* __restrict__ KL, double* __restrict__ KK) {
    __shared__ int w0_sh;
    if (threadIdx.x == 0) w0_sh = coarse_window(KL, KK);
    __syncthreads();
    const int s0 = w0_sh;

    int ti, tj;
    tri_decode(blockIdx.x, NT64, ti, tj);
    const double w = (ti == tj) ? 1.0 : 2.0;

    float dv[4][4];
    d2_tile(x, sq, ti, tj, dv);
    float lv[4][4];
    load_lk(lkp, ti, tj, lv);

    v2f nd[8], ll[8];
#pragma unroll
    for (int ct = 0; ct < 4; ++ct) {
        nd[ct * 2 + 0] = (v2f){-dv[ct][0], -dv[ct][1]};
        nd[ct * 2 + 1] = (v2f){-dv[ct][2], -dv[ct][3]};
        ll[ct * 2 + 0] = (v2f){lv[ct][0], lv[ct][1]};
        ll[ct * 2 + 1] = (v2f){lv[ct][2], lv[ct][3]};
    }

    __shared__ double part[4][10];
    const int lane = threadIdx.x & 63, wave = threadIdx.x >> 6;

    float c[5];
#pragma unroll
    for (int q = 0; q < 5; ++q)
        c[q] = __int_as_float(__builtin_amdgcn_readfirstlane(
                   __float_as_int(csig[s0 + q])));
    v2f akl[5], akk[5];
#pragma unroll
    for (int q = 0; q < 5; ++q) { akl[q] = (v2f){0.f, 0.f}; akk[q] = (v2f){0.f, 0.f}; }
#pragma unroll
    for (int e = 0; e < 8; ++e) {
        v2f ndv = nd[e], L = ll[e];
#pragma unroll
        for (int q = 0; q < 5; ++q) {
            v2f arg = ndv * c[q];
            v2f K = {fexp2(arg.x), fexp2(arg.y)};
            akl[q] = __builtin_elementwise_fma(K, L, akl[q]);
            akk[q] = __builtin_elementwise_fma(K, K, akk[q]);
        }
    }
#pragma unroll
    for (int q = 0; q < 5; ++q) {
        float v1 = wave_sum(akl[q].x + akl[q].y);
        float v2 = wave_sum(akk[q].x + akk[q].y);
        if (lane == 63) { part[wave][q] = (double)v1; part[wave][5 + q] = (double)v2; }
    }
    __syncthreads();
    const int t = threadIdx.x;
    if (t < 10) {
        double v = w * (part[0][t] + part[1][t] + part[2][t] + part[3][t]);
        if (t < 5) atomicAdd(&KL[25 + t], v);
        else       atomicAdd(&KK[25 + t - 5], v);
    }
}

// Final: full grid (4096 tiles), recompute d2, A = exp2(-d2*c)/n, coalesced
// per-tile writes (no mirror scatter). copt recomputed per block.
__launch_bounds__(256)
__global__ void k_final(const float* __restrict__ x, const float* __restrict__ sq,
                        const double* __restrict__ KL, const double* __restrict__ KK,
                        const float* __restrict__ csig, float* __restrict__ A) {
    __shared__ float cc_sh;
    if (threadIdx.x == 0) {
        int wv = coarse_window(KL, KK);
        double best = -1.0;
        int bk = 0;
        for (int k = 0; k < 5; ++k) {
            double loss = KL[25 + k] / sqrt(KK[25 + k]);
            if (loss > best) { best = loss; bk = k; }
        }
        cc_sh = csig[wv + bk];
    }
    __syncthreads();
    const float cc = cc_sh;
    const float inv_n = 1.0f / (float)NN;

    const int ti = blockIdx.x >> 6, tj = blockIdx.x & 63;

    float dv[4][4];
    d2_tile(x, sq, ti, tj, dv);

    const int l = threadIdx.x & 63, wid = threadIdx.x >> 6;
    const int rb = ti * 64 + wid * 16 + (l >> 4) * 4;
    const int cb = tj * 64 + (l & 15);
#pragma unroll
    for (int ct = 0; ct < 4; ++ct)
#pragma unroll
        for (int v = 0; v < 4; ++v)
            A[(size_t)(rb + v) * NN + cb + ct * 16] = fexp2(-dv[ct][v] * cc) * inv_n;
}

extern "C" void kernel_launch(void* const* d_in, const int* in_sizes, int n_in,
                              void* d_out, int out_size, void* d_ws, size_t ws_size,
                              hipStream_t stream) {
    const float* x  = (const float*)d_in[0];
    const float* lk = (const float*)d_in[1];
    float* out = (float*)d_out;
    char* ws = (char*)d_ws;

    double* dsum = (double*)(ws + WS_DSUM);
    unsigned long long* nzc = (unsigned long long*)(ws + WS_NZC);
    double* KL = (double*)(ws + WS_KL);
    double* KK = (double*)(ws + WS_KK);
    float* sqv  = (float*)(ws + WS_SQ);
    float* csig = (float*)(ws + WS_CSIG);

    hipLaunchKernelGGL(k_rowsq, dim3(NN / 256), dim3(256), 0, stream, x, sqv, dsum, nzc);
    hipLaunchKernelGGL(k_mean, dim3(GRID_TRI), dim3(256), 0, stream, x, sqv, dsum, nzc);
    hipLaunchKernelGGL(k_sigmas, dim3(1), dim3(128), 0, stream, dsum, nzc, csig, KL, KK);
    hipLaunchKernelGGL(k_sweep_coarse, dim3(GRID_TRI), dim3(256), 0, stream,
                       x, sqv, lk, csig, KL, KK);
    hipLaunchKernelGGL(k_sweep_refine, dim3(GRID_TRI), dim3(256), 0, stream,
                       x, sqv, lk, csig, KL, KK);
    hipLaunchKernelGGL(k_final, dim3(GRID_FULL), dim3(256), 0, stream,
                       x, sqv, KL, KK, csig, out);
}

// Round 17
// 178.240 us; speedup vs baseline: 1.7225x; 1.7225x over previous
//
#include <hip/hip_runtime.h>
#include <hip/hip_bf16.h>

#define NN 4096
#define DD 128
#define NS 75
#define TOT (NN * NN)

// k_d2 tiling (MFMA): 128x128 block, 4 waves, 64x64 per wave
#define BT 128
#define NBD2 (NN / BT)                      // 32
#define GRID_D2 (NBD2 * (NBD2 + 1) / 2)     // 528

// sweep tiling: 64x64 tiles, 256 threads, 16 elems/thread (register-resident)
#define SB 64
#define NBSW (NN / SB)                      // 64
#define GRID_SW (NBSW * (NBSW + 1) / 2)     // 2080

typedef float v2f __attribute__((ext_vector_type(2)));
typedef float f32x4 __attribute__((ext_vector_type(4)));
typedef short bf16x8 __attribute__((ext_vector_type(8)));

__device__ __forceinline__ float fexp2(float v) { return __builtin_amdgcn_exp2f(v); }

// DPP lane-shift add: no LDS/ds_bpermute latency (register-file crossing, ~2cy).
template <int CTRL>
__device__ __forceinline__ float dpp_add(float x) {
    int y = __builtin_amdgcn_update_dpp(0, __float_as_int(x), CTRL, 0xf, 0xf, true);
    return x + __int_as_float(y);
}
// Full wave64 sum; result lands in lane 63. Canonical gfx9 sequence.
__device__ __forceinline__ float wave_sum(float x) {
    x = dpp_add<0x111>(x);   // row_shr:1
    x = dpp_add<0x112>(x);   // row_shr:2
    x = dpp_add<0x114>(x);   // row_shr:4
    x = dpp_add<0x118>(x);   // row_shr:8
    x = dpp_add<0x142>(x);   // row_bcast:15
    x = dpp_add<0x143>(x);   // row_bcast:31 -> lane63 = wave sum
    return x;
}

// linear index -> (bi, bj) with bi <= bj, row-major over upper triangle
__device__ __forceinline__ void tri_decode(int t, int nb, int& bi, int& bj) {
    int b = 0, rem = t;
    while (rem >= nb - b) { rem -= nb - b; ++b; }
    bi = b; bj = b + rem;
}

// Split f32 -> bf16 hi + bf16 lo (exact residual truncated).
__device__ __forceinline__ void cvt_split(const float4& v0, const float4& v1,
                                          bf16x8& hi, bf16x8& lo) {
    float f[8] = {v0.x, v0.y, v0.z, v0.w, v1.x, v1.y, v1.z, v1.w};
#pragma unroll
    for (int j = 0; j < 8; ++j) {
        unsigned b = __float_as_uint(f[j]);
        hi[j] = (short)(b >> 16);
        float l = f[j] - __uint_as_float(b & 0xFFFF0000u);
        lo[j] = (short)(__float_as_uint(l) >> 16);
    }
}

// Coarse window logic (deterministic; recomputed per consumer block).
__device__ __forceinline__ int coarse_window(const double* KL, const double* KK) {
    double best = -1.0;
    int bk = 0;
    for (int k = 0; k < 25; ++k) {
        double loss = KL[k] / sqrt(KK[k]);
        if (loss > best) { best = loss; bk = k; }   // strict > = first max
    }
    int wv = 3 * bk - 2;
    if (wv < 0) wv = 0;
    if (wv > NS - 5) wv = NS - 5;
    return wv;
}

// ---------------- ws layout (bytes) ----------------
#define WS_DSUM 0                      // double
#define WS_NZC  8                      // unsigned long long
#define WS_KL   16                     // double[32]  (0..24 coarse, 25..29 refine)
#define WS_KK   (16 + 256)             // double[32]
#define WS_SQ   (16 + 512)             // float[NN]
#define WS_CSIG (WS_SQ + 4 * NN)       // float[NS]

__global__ void k_rowsq(const float* __restrict__ x, float* __restrict__ sq,
                        double* __restrict__ dsum, unsigned long long* __restrict__ nzc) {
    int tid = blockIdx.x * blockDim.x + threadIdx.x;
    if (tid == 0) { *dsum = 0.0; *nzc = 0ull; }
    if (tid < NN) {
        const float4* row = (const float4*)(x + (size_t)tid * DD);
        float s = 0.f;
#pragma unroll
        for (int i = 0; i < DD / 4; ++i) {
            float4 v = row[i];
            s += v.x * v.x + v.y * v.y + v.z * v.z + v.w * v.w;
        }
        sq[tid] = s;
    }
}

// d2 via split-bf16 MFMA: G = hi.hi^T + hi.lo^T + lo.hi^T (lo.lo dropped).
__launch_bounds__(256)
__global__ void k_d2(const float* __restrict__ x, const float* __restrict__ sq,
                     float* __restrict__ d2, double* __restrict__ dsum,
                     unsigned long long* __restrict__ nzc) {
    __shared__ double red_d[4];
    __shared__ int red_n[4];

    int bi, bj;
    tri_decode(blockIdx.x, NBD2, bi, bj);
    const int r0 = bi * BT, c0 = bj * BT;
    const int tid = threadIdx.x;
    const int l  = tid & 63, wid = tid >> 6;
    const int wr = wid >> 1, wc = wid & 1;
    const int lr = l & 15;
    const int lk = (l >> 4) * 8;
    const int l4 = (l >> 4) * 4;

    const int ar = r0 + wr * 64 + lr;
    const int br = c0 + wc * 64 + lr;

    f32x4 acc[4][4];
#pragma unroll
    for (int a = 0; a < 4; ++a)
#pragma unroll
        for (int b = 0; b < 4; ++b) acc[a][b] = (f32x4){0.f, 0.f, 0.f, 0.f};

#pragma unroll 1
    for (int kc = 0; kc < 4; ++kc) {
        const int k0 = kc * 32 + lk;
        bf16x8 ah[4], al[4], bh[4], bl[4];
#pragma unroll
        for (int t = 0; t < 4; ++t) {
            const float* pa = x + (size_t)(ar + t * 16) * DD + k0;
            float4 a0 = *(const float4*)pa;
            float4 a1 = *(const float4*)(pa + 4);
            cvt_split(a0, a1, ah[t], al[t]);
            const float* pb = x + (size_t)(br + t * 16) * DD + k0;
            float4 b0 = *(const float4*)pb;
            float4 b1 = *(const float4*)(pb + 4);
            cvt_split(b0, b1, bh[t], bl[t]);
        }
#pragma unroll
        for (int a = 0; a < 4; ++a)
#pragma unroll
            for (int b = 0; b < 4; ++b) {
                acc[a][b] = __builtin_amdgcn_mfma_f32_16x16x32_bf16(ah[a], bh[b], acc[a][b], 0, 0, 0);
                acc[a][b] = __builtin_amdgcn_mfma_f32_16x16x32_bf16(ah[a], bl[b], acc[a][b], 0, 0, 0);
                acc[a][b] = __builtin_amdgcn_mfma_f32_16x16x32_bf16(al[a], bh[b], acc[a][b], 0, 0, 0);
            }
    }

    float myd = 0.f;
    int myn = 0;
#pragma unroll
    for (int a = 0; a < 4; ++a) {
        const int grb = r0 + wr * 64 + a * 16 + l4;
        float4 sqr = *(const float4*)(sq + grb);
        float sr[4] = {sqr.x, sqr.y, sqr.z, sqr.w};
#pragma unroll
        for (int b = 0; b < 4; ++b) {
            const int gc = c0 + wc * 64 + b * 16 + lr;
            const float sc = sq[gc];
            float dv[4];
#pragma unroll
            for (int v = 0; v < 4; ++v) {
                float d = fmaxf(sr[v] + sc - 2.f * acc[a][b][v], 0.f);
                dv[v] = d;
                if (d > 0.f) { myd += sqrtf(d); ++myn; }
                d2[(size_t)(grb + v) * NN + gc] = d;
            }
            if (bi != bj) {
                float4 o = {dv[0], dv[1], dv[2], dv[3]};
                *(float4*)(d2 + (size_t)gc * NN + grb) = o;
            }
        }
    }

    const int w = (bi == bj) ? 1 : 2;
    float sd = wave_sum(myd);
    float sn = wave_sum((float)myn);
    if ((tid & 63) == 63) { red_d[wid] = (double)sd; red_n[wid] = (int)sn; }
    __syncthreads();
    if (tid == 0) {
        double td = red_d[0] + red_d[1] + red_d[2] + red_d[3];
        int tn = red_n[0] + red_n[1] + red_n[2] + red_n[3];
        atomicAdd(dsum, td * (double)w);
        atomicAdd(nzc, (unsigned long long)(tn * w));
    }
}

__global__ void k_sigmas(const double* __restrict__ dsum, const unsigned long long* __restrict__ nzc,
                         float* __restrict__ csig, double* __restrict__ KL, double* __restrict__ KK) {
    int t = threadIdx.x;
    float mean = (float)(*dsum / (double)(*nzc));
    float lo = 0.1f * mean;
    float hi = 10.0f * mean;
    float step = (hi - lo) / (float)NS;
    if (t < NS) {
        float s = lo + step * (float)t;
        csig[t] = (float)(1.4426950408889634 / ((double)s * (double)s));
    }
    if (t < 32) { KL[t] = 0.0; KK[t] = 0.0; }
}

// One sigma-phase over register-resident data.
template <int CH, int S0, int STRIDE, int NSLOT>
__device__ __forceinline__ void sweep_phase(const v2f* nd, const v2f* ll,
                                            const float* __restrict__ csig, int off,
                                            double part[4][2 * NSLOT],
                                            int wave, int lane, float w) {
    float c[CH];
#pragma unroll
    for (int s = 0; s < CH; ++s)   // force SGPR residency
        c[s] = __int_as_float(__builtin_amdgcn_readfirstlane(
                   __float_as_int(csig[off + STRIDE * (S0 + s)])));
    v2f akl[CH], akk[CH];
#pragma unroll
    for (int s = 0; s < CH; ++s) { akl[s] = (v2f){0.f, 0.f}; akk[s] = (v2f){0.f, 0.f}; }

#pragma unroll
    for (int e = 0; e < 8; ++e) {
        v2f ndv = nd[e], L = ll[e];
#pragma unroll
        for (int s = 0; s < CH; ++s) {
            v2f arg = ndv * c[s];                               // v_pk_mul_f32
            v2f K = {fexp2(arg.x), fexp2(arg.y)};               // 2x v_exp_f32
            akl[s] = __builtin_elementwise_fma(K, L, akl[s]);   // v_pk_fma_f32
            akk[s] = __builtin_elementwise_fma(K, K, akk[s]);
        }
    }

#pragma unroll
    for (int s = 0; s < CH; ++s) {
        float v1 = wave_sum(akl[s].x + akl[s].y);
        float v2 = wave_sum(akk[s].x + akk[s].y);
        if (lane == 63) {
            part[wave][S0 + s]         = (double)(v1 * w);
            part[wave][NSLOT + S0 + s] = (double)(v2 * w);
        }
    }
}

// Async batched tile load: all 8 dwordx4 loads issued back-to-back via one
// asm block with forced arch-VGPR landing regs ("=&v"), then a single
// vmcnt(0) that every value flows through. This defeats the AGPR-demotion
// load SERIALIZATION (R13-15: ~10K cy/wave fixed stall = 8 x ~600cy L3
// latencies paid serially because <32 arch VGPRs left no landing space).
__device__ __forceinline__ void sweep_load(const float* __restrict__ d2,
                                           const float* __restrict__ lk,
                                           int r0, int c0, v2f* nd, v2f* ll) {
    const int rr = threadIdx.x >> 4;
    const int c4 = (threadIdx.x & 15) * 4;
    const size_t base = (size_t)(r0 + rr) * NN + c0 + c4;

    const float* a0 = d2 + base;
    const float* a1 = d2 + base + (size_t)16 * NN;
    const float* a2 = d2 + base + (size_t)32 * NN;
    const float* a3 = d2 + base + (size_t)48 * NN;
    const float* b0 = lk + base;
    const float* b1 = lk + base + (size_t)16 * NN;
    const float* b2 = lk + base + (size_t)32 * NN;
    const float* b3 = lk + base + (size_t)48 * NN;

    f32x4 d0, d1, d2v, d3, l0, l1, l2, l3;
    asm volatile(
        "global_load_dwordx4 %0, %8, off\n\t"
        "global_load_dwordx4 %1, %9, off\n\t"
        "global_load_dwordx4 %2, %10, off\n\t"
        "global_load_dwordx4 %3, %11, off\n\t"
        "global_load_dwordx4 %4, %12, off\n\t"
        "global_load_dwordx4 %5, %13, off\n\t"
        "global_load_dwordx4 %6, %14, off\n\t"
        "global_load_dwordx4 %7, %15, off"
        : "=&v"(d0), "=&v"(d1), "=&v"(d2v), "=&v"(d3),
          "=&v"(l0), "=&v"(l1), "=&v"(l2), "=&v"(l3)
        : "v"(a0), "v"(a1), "v"(a2), "v"(a3),
          "v"(b0), "v"(b1), "v"(b2), "v"(b3));
    asm volatile("s_waitcnt vmcnt(0)"
        : "+v"(d0), "+v"(d1), "+v"(d2v), "+v"(d3),
          "+v"(l0), "+v"(l1), "+v"(l2), "+v"(l3));
    __builtin_amdgcn_sched_barrier(0);

    nd[0] = (v2f){-d0[0], -d0[1]}; nd[1] = (v2f){-d0[2], -d0[3]};
    nd[2] = (v2f){-d1[0], -d1[1]}; nd[3] = (v2f){-d1[2], -d1[3]};
    nd[4] = (v2f){-d2v[0], -d2v[1]}; nd[5] = (v2f){-d2v[2], -d2v[3]};
    nd[6] = (v2f){-d3[0], -d3[1]}; nd[7] = (v2f){-d3[2], -d3[3]};
    ll[0] = (v2f){l0[0], l0[1]}; ll[1] = (v2f){l0[2], l0[3]};
    ll[2] = (v2f){l1[0], l1[1]}; ll[3] = (v2f){l1[2], l1[3]};
    ll[4] = (v2f){l2[0], l2[1]}; ll[5] = (v2f){l2[2], l2[3]};
    ll[6] = (v2f){l3[0], l3[1]}; ll[7] = (v2f){l3[2], l3[3]};
}

// Coarse: 25 stride-3 sigmas, two wide phases CH=13 + CH=12.
__launch_bounds__(256, 3)
__global__ void k_sweep_coarse(const float* __restrict__ d2, const float* __restrict__ lk,
                               const float* __restrict__ csig, double* __restrict__ KL,
                               double* __restrict__ KK) {
    int bi, bj;
    tri_decode(blockIdx.x, NBSW, bi, bj);
    const int r0 = bi * SB, c0 = bj * SB;
    const float w = (bi == bj) ? 1.f : 2.f;

    v2f nd[8], ll[8];
    sweep_load(d2, lk, r0, c0, nd, ll);

    __shared__ double part[4][50];
    const int lane = threadIdx.x & 63, wave = threadIdx.x >> 6;

    sweep_phase<13, 0, 3, 25>(nd, ll, csig, 0, part, wave, lane, w);
    sweep_phase<12, 13, 3, 25>(nd, ll, csig, 0, part, wave, lane, w);

    __syncthreads();
    const int t = threadIdx.x;
    if (t < 50) {
        double v = part[0][t] + part[1][t] + part[2][t] + part[3][t];
        if (t < 25) atomicAdd(&KL[t], v);
        else        atomicAdd(&KK[t - 25], v);
    }
}

// Refine: window recomputed per block (deterministic), 5 stride-1 sigmas,
// slots 25..29.
__launch_bounds__(256, 3)
__global__ void k_sweep_refine(const float* __restrict__ d2, const float* __restrict__ lk,
                               const float* __restrict__ csig, double* __restrict__ KL,
                               double* __restrict__ KK) {
    __shared__ int w0_sh;
    if (threadIdx.x == 0) w0_sh = coarse_window(KL, KK);
    __syncthreads();
    const int s0 = w0_sh;

    int bi, bj;
    tri_decode(blockIdx.x, NBSW, bi, bj);
    const int r0 = bi * SB, c0 = bj * SB;
    const float w = (bi == bj) ? 1.f : 2.f;

    v2f nd[8], ll[8];
    sweep_load(d2, lk, r0, c0, nd, ll);

    __shared__ double part[4][10];
    const int lane = threadIdx.x & 63, wave = threadIdx.x >> 6;

    sweep_phase<5, 0, 1, 5>(nd, ll, csig, s0, part, wave, lane, w);

    __syncthreads();
    const int t = threadIdx.x;
    if (t < 10) {
        double v = part[0][t] + part[1][t] + part[2][t] + part[3][t];
        if (t < 5) atomicAdd(&KL[25 + t], v);
        else       atomicAdd(&KK[25 + t - 5], v);
    }
}

// Final: recompute copt per block, then A = exp2(-d2*c)/n over upper-tri
// blocks with mirror writes.
__launch_bounds__(256)
__global__ void k_final(float* __restrict__ d2, const double* __restrict__ KL,
                        const double* __restrict__ KK, const float* __restrict__ csig) {
    __shared__ float cc_sh;
    if (threadIdx.x == 0) {
        int wv = coarse_window(KL, KK);
        double best = -1.0;
        int bk = 0;
        for (int k = 0; k < 5; ++k) {
            double loss = KL[25 + k] / sqrt(KK[25 + k]);
            if (loss > best) { best = loss; bk = k; }
        }
        cc_sh = csig[wv + bk];
    }
    __syncthreads();
    const float cc = cc_sh;
    const float inv_n = 1.0f / (float)NN;

    int bi, bj;
    tri_decode(blockIdx.x, NBD2, bi, bj);
    const int r0 = bi * BT, c0 = bj * BT;
    const int tx = threadIdx.x & 31, ty = threadIdx.x >> 5;

    float a[16][4];
#pragma unroll
    for (int r = 0; r < 16; ++r) {
        size_t off = (size_t)(r0 + ty * 16 + r) * NN + c0 + tx * 4;
        float4 v = *(const float4*)(d2 + off);
        a[r][0] = fexp2(-v.x * cc) * inv_n;
        a[r][1] = fexp2(-v.y * cc) * inv_n;
        a[r][2] = fexp2(-v.z * cc) * inv_n;
        a[r][3] = fexp2(-v.w * cc) * inv_n;
        float4 o = {a[r][0], a[r][1], a[r][2], a[r][3]};
        *(float4*)(d2 + off) = o;
    }
    if (bi != bj) {
#pragma unroll
        for (int c = 0; c < 4; ++c) {
            size_t base = (size_t)(c0 + tx * 4 + c) * NN + r0 + ty * 16;
            float4 w0 = {a[0][c],  a[1][c],  a[2][c],  a[3][c]};
            float4 w1 = {a[4][c],  a[5][c],  a[6][c],  a[7][c]};
            float4 w2 = {a[8][c],  a[9][c],  a[10][c], a[11][c]};
            float4 w3 = {a[12][c], a[13][c], a[14][c], a[15][c]};
            *(float4*)(d2 + base + 0)  = w0;
            *(float4*)(d2 + base + 4)  = w1;
            *(float4*)(d2 + base + 8)  = w2;
            *(float4*)(d2 + base + 12) = w3;
        }
    }
}

extern "C" void kernel_launch(void* const* d_in, const int* in_sizes, int n_in,
                              void* d_out, int out_size, void* d_ws, size_t ws_size,
                              hipStream_t stream) {
    const float* x  = (const float*)d_in[0];
    const float* lk = (const float*)d_in[1];
    float* out = (float*)d_out;   // doubles as the d2 buffer, transformed in place
    char* ws = (char*)d_ws;

    double* dsum = (double*)(ws + WS_DSUM);
    unsigned long long* nzc = (unsigned long long*)(ws + WS_NZC);
    double* KL = (double*)(ws + WS_KL);
    double* KK = (double*)(ws + WS_KK);
    float* sqv  = (float*)(ws + WS_SQ);
    float* csig = (float*)(ws + WS_CSIG);

    hipLaunchKernelGGL(k_rowsq, dim3(NN / 256), dim3(256), 0, stream, x, sqv, dsum, nzc);
    hipLaunchKernelGGL(k_d2, dim3(GRID_D2), dim3(256), 0, stream, x, sqv, out, dsum, nzc);
    hipLaunchKernelGGL(k_sigmas, dim3(1), dim3(128), 0, stream, dsum, nzc, csig, KL, KK);
    hipLaunchKernelGGL(k_sweep_coarse, dim3(GRID_SW), dim3(256), 0, stream, out, lk, csig, KL, KK);
    hipLaunchKernelGGL(k_sweep_refine, dim3(GRID_SW), dim3(256), 0, stream, out, lk, csig, KL, KK);
    hipLaunchKernelGGL(k_final, dim3(GRID_D2), dim3(256), 0, stream, out, KL, KK, csig);
}

// Round 18
// 150.952 us; speedup vs baseline: 2.0339x; 1.1808x over previous
//
#include <hip/hip_runtime.h>
#include <hip/hip_bf16.h>

#define NN 4096
#define DD 128
#define NS 75

// k_d2 tiling (MFMA): 128x128 block, 4 waves, 64x64 per wave
#define BT 128
#define NBD2 (NN / BT)                      // 32
#define GRID_D2 (NBD2 * (NBD2 + 1) / 2)     // 528

// sweep tiling: 64x64 tiles, upper triangle; 2 tiles per block
#define SB 64
#define NBSW (NN / SB)                      // 64
#define NTILES (NBSW * (NBSW + 1) / 2)      // 2080
#define GRID_SW (NTILES / 2)                // 1040

typedef float v2f __attribute__((ext_vector_type(2)));
typedef float f32x4 __attribute__((ext_vector_type(4)));
typedef short bf16x8 __attribute__((ext_vector_type(8)));

__device__ __forceinline__ float fexp2(float v) { return __builtin_amdgcn_exp2f(v); }

// async global->LDS, 16B per lane; lds dst is wave-uniform base (HW adds lane*16)
__device__ __forceinline__ void gload_lds16(const void* g, void* l) {
    __builtin_amdgcn_global_load_lds(
        (const __attribute__((address_space(1))) unsigned int*)g,
        (__attribute__((address_space(3))) unsigned int*)l,
        16, 0, 0);
}

// DPP lane-shift add: register-file crossing, no LDS latency.
template <int CTRL>
__device__ __forceinline__ float dpp_add(float x) {
    int y = __builtin_amdgcn_update_dpp(0, __float_as_int(x), CTRL, 0xf, 0xf, true);
    return x + __int_as_float(y);
}
__device__ __forceinline__ float wave_sum(float x) {   // result in lane 63
    x = dpp_add<0x111>(x);
    x = dpp_add<0x112>(x);
    x = dpp_add<0x114>(x);
    x = dpp_add<0x118>(x);
    x = dpp_add<0x142>(x);
    x = dpp_add<0x143>(x);
    return x;
}

// linear index -> (bi, bj) with bi <= bj, row-major over upper triangle
__device__ __forceinline__ void tri_decode(int t, int nb, int& bi, int& bj) {
    int b = 0, rem = t;
    while (rem >= nb - b) { rem -= nb - b; ++b; }
    bi = b; bj = b + rem;
}

// Split f32 -> bf16 hi + bf16 lo (exact residual truncated).
__device__ __forceinline__ void cvt_split(const float4& v0, const float4& v1,
                                          bf16x8& hi, bf16x8& lo) {
    float f[8] = {v0.x, v0.y, v0.z, v0.w, v1.x, v1.y, v1.z, v1.w};
#pragma unroll
    for (int j = 0; j < 8; ++j) {
        unsigned b = __float_as_uint(f[j]);
        hi[j] = (short)(b >> 16);
        float l = f[j] - __uint_as_float(b & 0xFFFF0000u);
        lo[j] = (short)(__float_as_uint(l) >> 16);
    }
}

// Coarse window logic (deterministic; recomputed per consumer block).
__device__ __forceinline__ int coarse_window(const double* KL, const double* KK) {
    double best = -1.0;
    int bk = 0;
    for (int k = 0; k < 25; ++k) {
        double loss = KL[k] / sqrt(KK[k]);
        if (loss > best) { best = loss; bk = k; }   // strict > = first max
    }
    int wv = 3 * bk - 2;
    if (wv < 0) wv = 0;
    if (wv > NS - 5) wv = NS - 5;
    return wv;
}

// ---------------- ws layout (bytes) ----------------
#define WS_DSUM 0                      // double
#define WS_NZC  8                      // unsigned long long
#define WS_KL   16                     // double[32]  (0..24 coarse, 25..29 refine)
#define WS_KK   (16 + 256)             // double[32]
#define WS_SQ   (16 + 512)             // float[NN]
#define WS_CSIG (WS_SQ + 4 * NN)       // float[NS]

__global__ void k_rowsq(const float* __restrict__ x, float* __restrict__ sq,
                        double* __restrict__ dsum, unsigned long long* __restrict__ nzc) {
    int tid = blockIdx.x * blockDim.x + threadIdx.x;
    if (tid == 0) { *dsum = 0.0; *nzc = 0ull; }
    if (tid < NN) {
        const float4* row = (const float4*)(x + (size_t)tid * DD);
        float s = 0.f;
#pragma unroll
        for (int i = 0; i < DD / 4; ++i) {
            float4 v = row[i];
            s += v.x * v.x + v.y * v.y + v.z * v.z + v.w * v.w;
        }
        sq[tid] = s;
    }
}

// d2 via split-bf16 MFMA: G = hi.hi^T + hi.lo^T + lo.hi^T (lo.lo dropped).
__launch_bounds__(256)
__global__ void k_d2(const float* __restrict__ x, const float* __restrict__ sq,
                     float* __restrict__ d2, double* __restrict__ dsum,
                     unsigned long long* __restrict__ nzc) {
    __shared__ double red_d[4];
    __shared__ int red_n[4];

    int bi, bj;
    tri_decode(blockIdx.x, NBD2, bi, bj);
    const int r0 = bi * BT, c0 = bj * BT;
    const int tid = threadIdx.x;
    const int l  = tid & 63, wid = tid >> 6;
    const int wr = wid >> 1, wc = wid & 1;
    const int lr = l & 15;
    const int lk = (l >> 4) * 8;
    const int l4 = (l >> 4) * 4;

    const int ar = r0 + wr * 64 + lr;
    const int br = c0 + wc * 64 + lr;

    f32x4 acc[4][4];
#pragma unroll
    for (int a = 0; a < 4; ++a)
#pragma unroll
        for (int b = 0; b < 4; ++b) acc[a][b] = (f32x4){0.f, 0.f, 0.f, 0.f};

#pragma unroll 1
    for (int kc = 0; kc < 4; ++kc) {
        const int k0 = kc * 32 + lk;
        bf16x8 ah[4], al[4], bh[4], bl[4];
#pragma unroll
        for (int t = 0; t < 4; ++t) {
            const float* pa = x + (size_t)(ar + t * 16) * DD + k0;
            float4 a0 = *(const float4*)pa;
            float4 a1 = *(const float4*)(pa + 4);
            cvt_split(a0, a1, ah[t], al[t]);
            const float* pb = x + (size_t)(br + t * 16) * DD + k0;
            float4 b0 = *(const float4*)pb;
            float4 b1 = *(const float4*)(pb + 4);
            cvt_split(b0, b1, bh[t], bl[t]);
        }
#pragma unroll
        for (int a = 0; a < 4; ++a)
#pragma unroll
            for (int b = 0; b < 4; ++b) {
                acc[a][b] = __builtin_amdgcn_mfma_f32_16x16x32_bf16(ah[a], bh[b], acc[a][b], 0, 0, 0);
                acc[a][b] = __builtin_amdgcn_mfma_f32_16x16x32_bf16(ah[a], bl[b], acc[a][b], 0, 0, 0);
                acc[a][b] = __builtin_amdgcn_mfma_f32_16x16x32_bf16(al[a], bh[b], acc[a][b], 0, 0, 0);
            }
    }

    float myd = 0.f;
    int myn = 0;
#pragma unroll
    for (int a = 0; a < 4; ++a) {
        const int grb = r0 + wr * 64 + a * 16 + l4;
        float4 sqr = *(const float4*)(sq + grb);
        float sr[4] = {sqr.x, sqr.y, sqr.z, sqr.w};
#pragma unroll
        for (int b = 0; b < 4; ++b) {
            const int gc = c0 + wc * 64 + b * 16 + lr;
            const float sc = sq[gc];
            float dv[4];
#pragma unroll
            for (int v = 0; v < 4; ++v) {
                float d = fmaxf(sr[v] + sc - 2.f * acc[a][b][v], 0.f);
                dv[v] = d;
                if (d > 0.f) { myd += sqrtf(d); ++myn; }
                d2[(size_t)(grb + v) * NN + gc] = d;
            }
            if (bi != bj) {
                float4 o = {dv[0], dv[1], dv[2], dv[3]};
                *(float4*)(d2 + (size_t)gc * NN + grb) = o;
            }
        }
    }

    const int w = (bi == bj) ? 1 : 2;
    float sd = wave_sum(myd);
    float sn = wave_sum((float)myn);
    if ((tid & 63) == 63) { red_d[wid] = (double)sd; red_n[wid] = (int)sn; }
    __syncthreads();
    if (tid == 0) {
        double td = red_d[0] + red_d[1] + red_d[2] + red_d[3];
        int tn = red_n[0] + red_n[1] + red_n[2] + red_n[3];
        atomicAdd(dsum, td * (double)w);
        atomicAdd(nzc, (unsigned long long)(tn * w));
    }
}

__global__ void k_sigmas(const double* __restrict__ dsum, const unsigned long long* __restrict__ nzc,
                         float* __restrict__ csig, double* __restrict__ KL, double* __restrict__ KK) {
    int t = threadIdx.x;
    float mean = (float)(*dsum / (double)(*nzc));
    float lo = 0.1f * mean;
    float hi = 10.0f * mean;
    float step = (hi - lo) / (float)NS;
    if (t < NS) {
        float s = lo + step * (float)t;
        csig[t] = (float)(1.4426950408889634 / ((double)s * (double)s));
    }
    if (t < 32) { KL[t] = 0.0; KK[t] = 0.0; }
}

// One sigma-phase over register-resident data. ADD=false stores w*v,
// ADD=true accumulates (second tile).
template <bool ADD, int CH, int S0, int STRIDE, int NSLOT>
__device__ __forceinline__ void sweep_phase(const v2f* nd, const v2f* ll,
                                            const float* __restrict__ csig, int off,
                                            double part[4][2 * NSLOT],
                                            int wave, int lane, float w) {
    float c[CH];
#pragma unroll
    for (int s = 0; s < CH; ++s)   // force SGPR residency
        c[s] = __int_as_float(__builtin_amdgcn_readfirstlane(
                   __float_as_int(csig[off + STRIDE * (S0 + s)])));
    v2f akl[CH], akk[CH];
#pragma unroll
    for (int s = 0; s < CH; ++s) { akl[s] = (v2f){0.f, 0.f}; akk[s] = (v2f){0.f, 0.f}; }

#pragma unroll
    for (int e = 0; e < 8; ++e) {
        v2f ndv = nd[e], L = ll[e];
#pragma unroll
        for (int s = 0; s < CH; ++s) {
            v2f arg = ndv * c[s];                               // v_pk_mul_f32
            v2f K = {fexp2(arg.x), fexp2(arg.y)};               // 2x v_exp_f32
            akl[s] = __builtin_elementwise_fma(K, L, akl[s]);   // v_pk_fma_f32
            akk[s] = __builtin_elementwise_fma(K, K, akk[s]);
        }
    }

#pragma unroll
    for (int s = 0; s < CH; ++s) {
        float v1 = wave_sum(akl[s].x + akl[s].y);
        float v2 = wave_sum(akk[s].x + akk[s].y);
        if (lane == 63) {
            if (ADD) {
                part[wave][S0 + s]         += (double)(v1 * w);
                part[wave][NSLOT + S0 + s] += (double)(v2 * w);
            } else {
                part[wave][S0 + s]         = (double)(v1 * w);
                part[wave][NSLOT + S0 + s] = (double)(v2 * w);
            }
        }
    }
}

// Direct (tile0) load: 16 elems/thread into registers.
__device__ __forceinline__ void sweep_load_direct(const float* __restrict__ d2,
                                                  const float* __restrict__ lk,
                                                  int r0, int c0, v2f* nd, v2f* ll) {
    const int rr = threadIdx.x >> 4;
    const int c4 = (threadIdx.x & 15) * 4;
#pragma unroll
    for (int it = 0; it < 4; ++it) {
        size_t off = (size_t)(r0 + rr + 16 * it) * NN + c0 + c4;
        float4 dv = *(const float4*)(d2 + off);
        float4 lv = *(const float4*)(lk + off);
        nd[it * 2 + 0] = (v2f){-dv.x, -dv.y};
        nd[it * 2 + 1] = (v2f){-dv.z, -dv.w};
        ll[it * 2 + 0] = (v2f){lv.x, lv.y};
        ll[it * 2 + 1] = (v2f){lv.z, lv.w};
    }
}

// Prefetch (tile1) via global_load_lds into this wave's 8KB LDS slot: no
// registers held across the sigma phases (defeats demotion/spill), loads
// stay in flight under tile0's compute. Slot q (1KB) holds load q: lane
// l's 16B at q*1024 + l*16. q=0..3: d2 rows, q=4..7: lk rows.
__device__ __forceinline__ void sweep_prefetch(const float* __restrict__ d2,
                                               const float* __restrict__ lk,
                                               int r0, int c0, char* wbuf) {
    const int l = threadIdx.x & 63;
    const int wave4 = (threadIdx.x >> 6) * 4;
    const int rr = wave4 + (l >> 4);           // matches direct rr for this lane
    const int c4 = (l & 15) * 4;
#pragma unroll
    for (int q = 0; q < 4; ++q) {
        size_t off = (size_t)(r0 + rr + 16 * q) * NN + c0 + c4;
        gload_lds16(d2 + off, wbuf + q * 1024);
        gload_lds16(lk + off, wbuf + (4 + q) * 1024);
    }
}

__device__ __forceinline__ void sweep_unpack(const char* wbuf, v2f* nd, v2f* ll) {
    const int l = threadIdx.x & 63;
#pragma unroll
    for (int q = 0; q < 4; ++q) {
        f32x4 dv = *(const f32x4*)(wbuf + q * 1024 + l * 16);
        f32x4 lv = *(const f32x4*)(wbuf + (4 + q) * 1024 + l * 16);
        nd[q * 2 + 0] = (v2f){-dv[0], -dv[1]};
        nd[q * 2 + 1] = (v2f){-dv[2], -dv[3]};
        ll[q * 2 + 0] = (v2f){lv[0], lv[1]};
        ll[q * 2 + 1] = (v2f){lv[2], lv[3]};
    }
}

// Coarse: 2 tiles/block; tile1 async-prefetched under tile0's 25-sigma compute.
__launch_bounds__(256, 3)
__global__ void k_sweep_coarse(const float* __restrict__ d2, const float* __restrict__ lk,
                               const float* __restrict__ csig, double* __restrict__ KL,
                               double* __restrict__ KK) {
    __shared__ char pbuf[4][8192];
    __shared__ double part[4][50];
    const int lane = threadIdx.x & 63, wave = threadIdx.x >> 6;

    int t0 = blockIdx.x * 2, t1 = t0 + 1;
    int bi0, bj0, bi1, bj1;
    tri_decode(t0, NBSW, bi0, bj0);
    tri_decode(t1, NBSW, bi1, bj1);
    const float w0 = (bi0 == bj0) ? 1.f : 2.f;
    const float w1 = (bi1 == bj1) ? 1.f : 2.f;

    // issue tile1 prefetch first (max overlap), then tile0 direct loads
    sweep_prefetch(d2, lk, bi1 * SB, bj1 * SB, &pbuf[wave][0]);
    v2f nd[8], ll[8];
    sweep_load_direct(d2, lk, bi0 * SB, bj0 * SB, nd, ll);

    sweep_phase<false, 13, 0, 3, 25>(nd, ll, csig, 0, part, wave, lane, w0);
    sweep_phase<false, 12, 13, 3, 25>(nd, ll, csig, 0, part, wave, lane, w0);

    asm volatile("s_waitcnt vmcnt(0)" ::: "memory");
    sweep_unpack(&pbuf[wave][0], nd, ll);

    sweep_phase<true, 13, 0, 3, 25>(nd, ll, csig, 0, part, wave, lane, w1);
    sweep_phase<true, 12, 13, 3, 25>(nd, ll, csig, 0, part, wave, lane, w1);

    __syncthreads();
    const int t = threadIdx.x;
    if (t < 50) {
        double v = part[0][t] + part[1][t] + part[2][t] + part[3][t];
        if (t < 25) atomicAdd(&KL[t], v);
        else        atomicAdd(&KK[t - 25], v);
    }
}

// Refine: same 2-tile structure, 5 stride-1 sigmas at the coarse window.
__launch_bounds__(256, 3)
__global__ void k_sweep_refine(const float* __restrict__ d2, const float* __restrict__ lk,
                               const float* __restrict__ csig, double* __restrict__ KL,
                               double* __restrict__ KK) {
    __shared__ char pbuf[4][8192];
    __shared__ double part[4][10];
    __shared__ int w0_sh;
    if (threadIdx.x == 0) w0_sh = coarse_window(KL, KK);
    const int lane = threadIdx.x & 63, wave = threadIdx.x >> 6;

    int t0 = blockIdx.x * 2, t1 = t0 + 1;
    int bi0, bj0, bi1, bj1;
    tri_decode(t0, NBSW, bi0, bj0);
    tri_decode(t1, NBSW, bi1, bj1);
    const float wt0 = (bi0 == bj0) ? 1.f : 2.f;
    const float wt1 = (bi1 == bj1) ? 1.f : 2.f;

    sweep_prefetch(d2, lk, bi1 * SB, bj1 * SB, &pbuf[wave][0]);
    v2f nd[8], ll[8];
    sweep_load_direct(d2, lk, bi0 * SB, bj0 * SB, nd, ll);
    __syncthreads();                 // w0_sh visible
    const int s0 = w0_sh;

    sweep_phase<false, 5, 0, 1, 5>(nd, ll, csig, s0, part, wave, lane, wt0);

    asm volatile("s_waitcnt vmcnt(0)" ::: "memory");
    sweep_unpack(&pbuf[wave][0], nd, ll);

    sweep_phase<true, 5, 0, 1, 5>(nd, ll, csig, s0, part, wave, lane, wt1);

    __syncthreads();
    const int t = threadIdx.x;
    if (t < 10) {
        double v = part[0][t] + part[1][t] + part[2][t] + part[3][t];
        if (t < 5) atomicAdd(&KL[25 + t], v);
        else       atomicAdd(&KK[25 + t - 5], v);
    }
}

// Final: recompute copt per block, then A = exp2(-d2*c)/n over upper-tri
// blocks with mirror writes.
__launch_bounds__(256)
__global__ void k_final(float* __restrict__ d2, const double* __restrict__ KL,
                        const double* __restrict__ KK, const float* __restrict__ csig) {
    __shared__ float cc_sh;
    if (threadIdx.x == 0) {
        int wv = coarse_window(KL, KK);
        double best = -1.0;
        int bk = 0;
        for (int k = 0; k < 5; ++k) {
            double loss = KL[25 + k] / sqrt(KK[25 + k]);
            if (loss > best) { best = loss; bk = k; }
        }
        cc_sh = csig[wv + bk];
    }
    __syncthreads();
    const float cc = cc_sh;
    const float inv_n = 1.0f / (float)NN;

    int bi, bj;
    tri_decode(blockIdx.x, NBD2, bi, bj);
    const int r0 = bi * BT, c0 = bj * BT;
    const int tx = threadIdx.x & 31, ty = threadIdx.x >> 5;

    float a[16][4];
#pragma unroll
    for (int r = 0; r < 16; ++r) {
        size_t off = (size_t)(r0 + ty * 16 + r) * NN + c0 + tx * 4;
        float4 v = *(const float4*)(d2 + off);
        a[r][0] = fexp2(-v.x * cc) * inv_n;
        a[r][1] = fexp2(-v.y * cc) * inv_n;
        a[r][2] = fexp2(-v.z * cc) * inv_n;
        a[r][3] = fexp2(-v.w * cc) * inv_n;
        float4 o = {a[r][0], a[r][1], a[r][2], a[r][3]};
        *(float4*)(d2 + off) = o;
    }
    if (bi != bj) {
#pragma unroll
        for (int c = 0; c < 4; ++c) {
            size_t base = (size_t)(c0 + tx * 4 + c) * NN + r0 + ty * 16;
            float4 w0 = {a[0][c],  a[1][c],  a[2][c],  a[3][c]};
            float4 w1 = {a[4][c],  a[5][c],  a[6][c],  a[7][c]};
            float4 w2 = {a[8][c],  a[9][c],  a[10][c], a[11][c]};
            float4 w3 = {a[12][c], a[13][c], a[14][c], a[15][c]};
            *(float4*)(d2 + base + 0)  = w0;
            *(float4*)(d2 + base + 4)  = w1;
            *(float4*)(d2 + base + 8)  = w2;
            *(float4*)(d2 + base + 12) = w3;
        }
    }
}

extern "C" void kernel_launch(void* const* d_in, const int* in_sizes, int n_in,
                              void* d_out, int out_size, void* d_ws, size_t ws_size,
                              hipStream_t stream) {
    const float* x  = (const float*)d_in[0];
    const float* lk = (const float*)d_in[1];
    float* out = (float*)d_out;   // doubles as the d2 buffer, transformed in place
    char* ws = (char*)d_ws;

    double* dsum = (double*)(ws + WS_DSUM);
    unsigned long long* nzc = (unsigned long long*)(ws + WS_NZC);
    double* KL = (double*)(ws + WS_KL);
    double* KK = (double*)(ws + WS_KK);
    float* sqv  = (float*)(ws + WS_SQ);
    float* csig = (float*)(ws + WS_CSIG);

    hipLaunchKernelGGL(k_rowsq, dim3(NN / 256), dim3(256), 0, stream, x, sqv, dsum, nzc);
    hipLaunchKernelGGL(k_d2, dim3(GRID_D2), dim3(256), 0, stream, x, sqv, out, dsum, nzc);
    hipLaunchKernelGGL(k_sigmas, dim3(1), dim3(128), 0, stream, dsum, nzc, csig, KL, KK);
    hipLaunchKernelGGL(k_sweep_coarse, dim3(GRID_SW), dim3(256), 0, stream, out, lk, csig, KL, KK);
    hipLaunchKernelGGL(k_sweep_refine, dim3(GRID_SW), dim3(256), 0, stream, out, lk, csig, KL, KK);
    hipLaunchKernelGGL(k_final, dim3(GRID_D2), dim3(256), 0, stream, out, KL, KK, csig);
}

// Round 19
// 147.655 us; speedup vs baseline: 2.0794x; 1.0223x over previous
//
#include <hip/hip_runtime.h>
#include <hip/hip_bf16.h>

#define NN 4096
#define DD 128
#define NS 75
#define TOT (NN * NN)

// k_d2 tiling (MFMA): 128x128 block, 4 waves, 64x64 per wave
#define BT 128
#define NBD2 (NN / BT)                      // 32
#define GRID_D2 (NBD2 * (NBD2 + 1) / 2)     // 528

// sweep tiling: 64x64 tiles, upper triangle; 2 tiles per block
#define SB 64
#define NBSW (NN / SB)                      // 64
#define NTILES (NBSW * (NBSW + 1) / 2)      // 2080
#define GRID_SW (NTILES / 2)                // 1040

typedef float v2f __attribute__((ext_vector_type(2)));
typedef float f32x4 __attribute__((ext_vector_type(4)));
typedef short bf16x8 __attribute__((ext_vector_type(8)));

__device__ __forceinline__ float fexp2(float v) { return __builtin_amdgcn_exp2f(v); }

// async global->LDS, 16B per lane; lds dst is wave-uniform base (HW adds lane*16)
__device__ __forceinline__ void gload_lds16(const void* g, void* l) {
    __builtin_amdgcn_global_load_lds(
        (const __attribute__((address_space(1))) unsigned int*)g,
        (__attribute__((address_space(3))) unsigned int*)l,
        16, 0, 0);
}

// DPP lane-shift add: register-file crossing, no LDS latency.
template <int CTRL>
__device__ __forceinline__ float dpp_add(float x) {
    int y = __builtin_amdgcn_update_dpp(0, __float_as_int(x), CTRL, 0xf, 0xf, true);
    return x + __int_as_float(y);
}
__device__ __forceinline__ float wave_sum(float x) {   // result in lane 63
    x = dpp_add<0x111>(x);
    x = dpp_add<0x112>(x);
    x = dpp_add<0x114>(x);
    x = dpp_add<0x118>(x);
    x = dpp_add<0x142>(x);
    x = dpp_add<0x143>(x);
    return x;
}

// linear index -> (bi, bj) with bi <= bj, row-major over upper triangle
__device__ __forceinline__ void tri_decode(int t, int nb, int& bi, int& bj) {
    int b = 0, rem = t;
    while (rem >= nb - b) { rem -= nb - b; ++b; }
    bi = b; bj = b + rem;
}

// Split f32 -> bf16 hi + bf16 lo (exact residual truncated).
__device__ __forceinline__ void cvt_split(const float4& v0, const float4& v1,
                                          bf16x8& hi, bf16x8& lo) {
    float f[8] = {v0.x, v0.y, v0.z, v0.w, v1.x, v1.y, v1.z, v1.w};
#pragma unroll
    for (int j = 0; j < 8; ++j) {
        unsigned b = __float_as_uint(f[j]);
        hi[j] = (short)(b >> 16);
        float l = f[j] - __uint_as_float(b & 0xFFFF0000u);
        lo[j] = (short)(__float_as_uint(l) >> 16);
    }
}

// Coarse window logic (deterministic; recomputed per consumer block).
__device__ __forceinline__ int coarse_window(const double* KL, const double* KK) {
    double best = -1.0;
    int bk = 0;
    for (int k = 0; k < 25; ++k) {
        double loss = KL[k] / sqrt(KK[k]);
        if (loss > best) { best = loss; bk = k; }   // strict > = first max
    }
    int wv = 3 * bk - 2;
    if (wv < 0) wv = 0;
    if (wv > NS - 5) wv = NS - 5;
    return wv;
}

// ---------------- ws layout (bytes) ----------------
#define WS_DSUM 0                      // double
#define WS_NZC  8                      // unsigned long long
#define WS_KL   16                     // double[32]  (0..24 coarse, 25..29 refine)
#define WS_KK   (16 + 256)             // double[32]
#define WS_SQ   (16 + 512)             // float[NN]
#define WS_CSIG (WS_SQ + 4 * NN)       // float[NS]

__global__ void k_rowsq(const float* __restrict__ x, float* __restrict__ sq,
                        double* __restrict__ dsum, unsigned long long* __restrict__ nzc) {
    int tid = blockIdx.x * blockDim.x + threadIdx.x;
    if (tid == 0) { *dsum = 0.0; *nzc = 0ull; }
    if (tid < NN) {
        const float4* row = (const float4*)(x + (size_t)tid * DD);
        float s = 0.f;
#pragma unroll
        for (int i = 0; i < DD / 4; ++i) {
            float4 v = row[i];
            s += v.x * v.x + v.y * v.y + v.z * v.z + v.w * v.w;
        }
        sq[tid] = s;
    }
}

// d2 via split-bf16 MFMA: G = hi.hi^T + hi.lo^T + lo.hi^T (lo.lo dropped).
// Epilogue: per-wave LDS transpose staging (two 32-row passes, wave-
// synchronous) -> coalesced writes: direct 4x256B, mirror 8x128B per instr.
// Fixes R18's 1.3TB/s write scatter (16B float4s at 16KB stride).
__launch_bounds__(256)
__global__ void k_d2(const float* __restrict__ x, const float* __restrict__ sq,
                     float* __restrict__ d2, double* __restrict__ dsum,
                     unsigned long long* __restrict__ nzc) {
    __shared__ float st[4][32][68];    // 34,816 B: per-wave 32x64 staging, pad 4
    __shared__ double red_d[4];
    __shared__ int red_n[4];

    int bi, bj;
    tri_decode(blockIdx.x, NBD2, bi, bj);
    const int r0 = bi * BT, c0 = bj * BT;
    const int tid = threadIdx.x;
    const int l  = tid & 63, wid = tid >> 6;
    const int wr = wid >> 1, wc = wid & 1;
    const int lr = l & 15;
    const int lk = (l >> 4) * 8;
    const int l4 = (l >> 4) * 4;

    const int ar = r0 + wr * 64 + lr;
    const int br = c0 + wc * 64 + lr;

    f32x4 acc[4][4];
#pragma unroll
    for (int a = 0; a < 4; ++a)
#pragma unroll
        for (int b = 0; b < 4; ++b) acc[a][b] = (f32x4){0.f, 0.f, 0.f, 0.f};

#pragma unroll 1
    for (int kc = 0; kc < 4; ++kc) {
        const int k0 = kc * 32 + lk;
        bf16x8 ah[4], al[4], bh[4], bl[4];
#pragma unroll
        for (int t = 0; t < 4; ++t) {
            const float* pa = x + (size_t)(ar + t * 16) * DD + k0;
            float4 a0 = *(const float4*)pa;
            float4 a1 = *(const float4*)(pa + 4);
            cvt_split(a0, a1, ah[t], al[t]);
            const float* pb = x + (size_t)(br + t * 16) * DD + k0;
            float4 b0 = *(const float4*)pb;
            float4 b1 = *(const float4*)(pb + 4);
            cvt_split(b0, b1, bh[t], bl[t]);
        }
#pragma unroll
        for (int a = 0; a < 4; ++a)
#pragma unroll
            for (int b = 0; b < 4; ++b) {
                acc[a][b] = __builtin_amdgcn_mfma_f32_16x16x32_bf16(ah[a], bh[b], acc[a][b], 0, 0, 0);
                acc[a][b] = __builtin_amdgcn_mfma_f32_16x16x32_bf16(ah[a], bl[b], acc[a][b], 0, 0, 0);
                acc[a][b] = __builtin_amdgcn_mfma_f32_16x16x32_bf16(al[a], bh[b], acc[a][b], 0, 0, 0);
            }
    }

    // d2 = max(sq_r + sq_c - 2G, 0) in-place into acc; dist-sum/nnz reduction.
    float myd = 0.f;
    int myn = 0;
#pragma unroll
    for (int a = 0; a < 4; ++a) {
        const int grb = r0 + wr * 64 + a * 16 + l4;
        float4 sqr = *(const float4*)(sq + grb);
        float sr[4] = {sqr.x, sqr.y, sqr.z, sqr.w};
#pragma unroll
        for (int b = 0; b < 4; ++b) {
            const float sc = sq[c0 + wc * 64 + b * 16 + lr];
#pragma unroll
            for (int v = 0; v < 4; ++v) {
                float d = fmaxf(sr[v] + sc - 2.f * acc[a][b][v], 0.f);
                acc[a][b][v] = d;
                if (d > 0.f) { myd += sqrtf(d); ++myn; }
            }
        }
    }

    // Staged, coalesced write-out (wave-synchronous LDS reuse, no barriers).
    const int row0 = r0 + wr * 64, col0 = c0 + wc * 64;
#pragma unroll
    for (int p = 0; p < 2; ++p) {
        // stage rows p*32 .. p*32+31 of the wave tile
#pragma unroll
        for (int ha = 0; ha < 2; ++ha) {
            const int a = 2 * p + ha;
#pragma unroll
            for (int b = 0; b < 4; ++b)
#pragma unroll
                for (int v = 0; v < 4; ++v)
                    st[wid][ha * 16 + l4 + v][b * 16 + lr] = acc[a][b][v];
        }
        // direct: 8 instrs, each 4 rows x 256B contiguous
#pragma unroll
        for (int q = 0; q < 8; ++q) {
            const int lr2 = q * 4 + (l >> 4);          // 0..31
            f32x4 vv = *(const f32x4*)&st[wid][lr2][(l & 15) * 4];
            *(f32x4*)(d2 + (size_t)(row0 + p * 32 + lr2) * NN + col0 + (l & 15) * 4) = vv;
        }
        if (bi != bj) {
            // mirror: 8 instrs, each 8 out-rows x 128B contiguous
#pragma unroll
            for (int q = 0; q < 8; ++q) {
                const int tc = q * 8 + (l >> 3);        // 0..63 (out-row in col block)
                const int trb = (l & 7) * 4;            // 0..28 (col base within pass)
                f32x4 vv = {st[wid][trb + 0][tc], st[wid][trb + 1][tc],
                            st[wid][trb + 2][tc], st[wid][trb + 3][tc]};
                *(f32x4*)(d2 + (size_t)(col0 + tc) * NN + row0 + p * 32 + trb) = vv;
            }
        }
    }

    const int w = (bi == bj) ? 1 : 2;
    float sd = wave_sum(myd);
    float sn = wave_sum((float)myn);
    if ((tid & 63) == 63) { red_d[wid] = (double)sd; red_n[wid] = (int)sn; }
    __syncthreads();
    if (tid == 0) {
        double td = red_d[0] + red_d[1] + red_d[2] + red_d[3];
        int tn = red_n[0] + red_n[1] + red_n[2] + red_n[3];
        atomicAdd(dsum, td * (double)w);
        atomicAdd(nzc, (unsigned long long)(tn * w));
    }
}

__global__ void k_sigmas(const double* __restrict__ dsum, const unsigned long long* __restrict__ nzc,
                         float* __restrict__ csig, double* __restrict__ KL, double* __restrict__ KK) {
    int t = threadIdx.x;
    float mean = (float)(*dsum / (double)(*nzc));
    float lo = 0.1f * mean;
    float hi = 10.0f * mean;
    float step = (hi - lo) / (float)NS;
    if (t < NS) {
        float s = lo + step * (float)t;
        csig[t] = (float)(1.4426950408889634 / ((double)s * (double)s));
    }
    if (t < 32) { KL[t] = 0.0; KK[t] = 0.0; }
}

// One sigma-phase over register-resident data. ADD=false stores w*v,
// ADD=true accumulates (second tile).
template <bool ADD, int CH, int S0, int STRIDE, int NSLOT>
__device__ __forceinline__ void sweep_phase(const v2f* nd, const v2f* ll,
                                            const float* __restrict__ csig, int off,
                                            double part[4][2 * NSLOT],
                                            int wave, int lane, float w) {
    float c[CH];
#pragma unroll
    for (int s = 0; s < CH; ++s)   // force SGPR residency
        c[s] = __int_as_float(__builtin_amdgcn_readfirstlane(
                   __float_as_int(csig[off + STRIDE * (S0 + s)])));
    v2f akl[CH], akk[CH];
#pragma unroll
    for (int s = 0; s < CH; ++s) { akl[s] = (v2f){0.f, 0.f}; akk[s] = (v2f){0.f, 0.f}; }

#pragma unroll
    for (int e = 0; e < 8; ++e) {
        v2f ndv = nd[e], L = ll[e];
#pragma unroll
        for (int s = 0; s < CH; ++s) {
            v2f arg = ndv * c[s];                               // v_pk_mul_f32
            v2f K = {fexp2(arg.x), fexp2(arg.y)};               // 2x v_exp_f32
            akl[s] = __builtin_elementwise_fma(K, L, akl[s]);   // v_pk_fma_f32
            akk[s] = __builtin_elementwise_fma(K, K, akk[s]);
        }
    }

#pragma unroll
    for (int s = 0; s < CH; ++s) {
        float v1 = wave_sum(akl[s].x + akl[s].y);
        float v2 = wave_sum(akk[s].x + akk[s].y);
        if (lane == 63) {
            if (ADD) {
                part[wave][S0 + s]         += (double)(v1 * w);
                part[wave][NSLOT + S0 + s] += (double)(v2 * w);
            } else {
                part[wave][S0 + s]         = (double)(v1 * w);
                part[wave][NSLOT + S0 + s] = (double)(v2 * w);
            }
        }
    }
}

// Direct (tile0) load: 16 elems/thread into registers.
__device__ __forceinline__ void sweep_load_direct(const float* __restrict__ d2,
                                                  const float* __restrict__ lk,
                                                  int r0, int c0, v2f* nd, v2f* ll) {
    const int rr = threadIdx.x >> 4;
    const int c4 = (threadIdx.x & 15) * 4;
#pragma unroll
    for (int it = 0; it < 4; ++it) {
        size_t off = (size_t)(r0 + rr + 16 * it) * NN + c0 + c4;
        float4 dv = *(const float4*)(d2 + off);
        float4 lv = *(const float4*)(lk + off);
        nd[it * 2 + 0] = (v2f){-dv.x, -dv.y};
        nd[it * 2 + 1] = (v2f){-dv.z, -dv.w};
        ll[it * 2 + 0] = (v2f){lv.x, lv.y};
        ll[it * 2 + 1] = (v2f){lv.z, lv.w};
    }
}

// Prefetch (tile1) via global_load_lds into this wave's 8KB LDS slot.
__device__ __forceinline__ void sweep_prefetch(const float* __restrict__ d2,
                                               const float* __restrict__ lk,
                                               int r0, int c0, char* wbuf) {
    const int l = threadIdx.x & 63;
    const int wave4 = (threadIdx.x >> 6) * 4;
    const int rr = wave4 + (l >> 4);
    const int c4 = (l & 15) * 4;
#pragma unroll
    for (int q = 0; q < 4; ++q) {
        size_t off = (size_t)(r0 + rr + 16 * q) * NN + c0 + c4;
        gload_lds16(d2 + off, wbuf + q * 1024);
        gload_lds16(lk + off, wbuf + (4 + q) * 1024);
    }
}

__device__ __forceinline__ void sweep_unpack(const char* wbuf, v2f* nd, v2f* ll) {
    const int l = threadIdx.x & 63;
#pragma unroll
    for (int q = 0; q < 4; ++q) {
        f32x4 dv = *(const f32x4*)(wbuf + q * 1024 + l * 16);
        f32x4 lv = *(const f32x4*)(wbuf + (4 + q) * 1024 + l * 16);
        nd[q * 2 + 0] = (v2f){-dv[0], -dv[1]};
        nd[q * 2 + 1] = (v2f){-dv[2], -dv[3]};
        ll[q * 2 + 0] = (v2f){lv[0], lv[1]};
        ll[q * 2 + 1] = (v2f){lv[2], lv[3]};
    }
}

// Coarse: 2 tiles/block; tile1 async-prefetched under tile0's 25-sigma compute.
__launch_bounds__(256, 3)
__global__ void k_sweep_coarse(const float* __restrict__ d2, const float* __restrict__ lk,
                               const float* __restrict__ csig, double* __restrict__ KL,
                               double* __restrict__ KK) {
    __shared__ char pbuf[4][8192];
    __shared__ double part[4][50];
    const int lane = threadIdx.x & 63, wave = threadIdx.x >> 6;

    int t0 = blockIdx.x * 2, t1 = t0 + 1;
    int bi0, bj0, bi1, bj1;
    tri_decode(t0, NBSW, bi0, bj0);
    tri_decode(t1, NBSW, bi1, bj1);
    const float w0 = (bi0 == bj0) ? 1.f : 2.f;
    const float w1 = (bi1 == bj1) ? 1.f : 2.f;

    sweep_prefetch(d2, lk, bi1 * SB, bj1 * SB, &pbuf[wave][0]);
    v2f nd[8], ll[8];
    sweep_load_direct(d2, lk, bi0 * SB, bj0 * SB, nd, ll);

    sweep_phase<false, 13, 0, 3, 25>(nd, ll, csig, 0, part, wave, lane, w0);
    sweep_phase<false, 12, 13, 3, 25>(nd, ll, csig, 0, part, wave, lane, w0);

    asm volatile("s_waitcnt vmcnt(0)" ::: "memory");
    sweep_unpack(&pbuf[wave][0], nd, ll);

    sweep_phase<true, 13, 0, 3, 25>(nd, ll, csig, 0, part, wave, lane, w1);
    sweep_phase<true, 12, 13, 3, 25>(nd, ll, csig, 0, part, wave, lane, w1);

    __syncthreads();
    const int t = threadIdx.x;
    if (t < 50) {
        double v = part[0][t] + part[1][t] + part[2][t] + part[3][t];
        if (t < 25) atomicAdd(&KL[t], v);
        else        atomicAdd(&KK[t - 25], v);
    }
}

// Refine: same 2-tile structure, 5 stride-1 sigmas at the coarse window.
__launch_bounds__(256, 3)
__global__ void k_sweep_refine(const float* __restrict__ d2, const float* __restrict__ lk,
                               const float* __restrict__ csig, double* __restrict__ KL,
                               double* __restrict__ KK) {
    __shared__ char pbuf[4][8192];
    __shared__ double part[4][10];
    __shared__ int w0_sh;
    if (threadIdx.x == 0) w0_sh = coarse_window(KL, KK);
    const int lane = threadIdx.x & 63, wave = threadIdx.x >> 6;

    int t0 = blockIdx.x * 2, t1 = t0 + 1;
    int bi0, bj0, bi1, bj1;
    tri_decode(t0, NBSW, bi0, bj0);
    tri_decode(t1, NBSW, bi1, bj1);
    const float wt0 = (bi0 == bj0) ? 1.f : 2.f;
    const float wt1 = (bi1 == bj1) ? 1.f : 2.f;

    sweep_prefetch(d2, lk, bi1 * SB, bj1 * SB, &pbuf[wave][0]);
    v2f nd[8], ll[8];
    sweep_load_direct(d2, lk, bi0 * SB, bj0 * SB, nd, ll);
    __syncthreads();                 // w0_sh visible
    const int s0 = w0_sh;

    sweep_phase<false, 5, 0, 1, 5>(nd, ll, csig, s0, part, wave, lane, wt0);

    asm volatile("s_waitcnt vmcnt(0)" ::: "memory");
    sweep_unpack(&pbuf[wave][0], nd, ll);

    sweep_phase<true, 5, 0, 1, 5>(nd, ll, csig, s0, part, wave, lane, wt1);

    __syncthreads();
    const int t = threadIdx.x;
    if (t < 10) {
        double v = part[0][t] + part[1][t] + part[2][t] + part[3][t];
        if (t < 5) atomicAdd(&KL[25 + t], v);
        else       atomicAdd(&KK[25 + t - 5], v);
    }
}

// Final: simple full-matrix grid-stride elementwise (the full d2 exists,
// both halves coalesced) — no scatter. copt recomputed per block.
__launch_bounds__(256)
__global__ void k_final(float* __restrict__ d2, const double* __restrict__ KL,
                        const double* __restrict__ KK, const float* __restrict__ csig) {
    __shared__ float cc_sh;
    if (threadIdx.x == 0) {
        int wv = coarse_window(KL, KK);
        double best = -1.0;
        int bk = 0;
        for (int k = 0; k < 5; ++k) {
            double loss = KL[25 + k] / sqrt(KK[25 + k]);
            if (loss > best) { best = loss; bk = k; }
        }
        cc_sh = csig[wv + bk];
    }
    __syncthreads();
    const float cc = cc_sh;
    const float inv_n = 1.0f / (float)NN;
    const int nthreads = gridDim.x * blockDim.x;
    float4* p = (float4*)d2;
    for (int i = blockIdx.x * blockDim.x + threadIdx.x; i < TOT / 4; i += nthreads) {
        float4 v = p[i];
        v.x = fexp2(-v.x * cc) * inv_n;
        v.y = fexp2(-v.y * cc) * inv_n;
        v.z = fexp2(-v.z * cc) * inv_n;
        v.w = fexp2(-v.w * cc) * inv_n;
        p[i] = v;
    }
}

extern "C" void kernel_launch(void* const* d_in, const int* in_sizes, int n_in,
                              void* d_out, int out_size, void* d_ws, size_t ws_size,
                              hipStream_t stream) {
    const float* x  = (const float*)d_in[0];
    const float* lk = (const float*)d_in[1];
    float* out = (float*)d_out;   // doubles as the d2 buffer, transformed in place
    char* ws = (char*)d_ws;

    double* dsum = (double*)(ws + WS_DSUM);
    unsigned long long* nzc = (unsigned long long*)(ws + WS_NZC);
    double* KL = (double*)(ws + WS_KL);
    double* KK = (double*)(ws + WS_KK);
    float* sqv  = (float*)(ws + WS_SQ);
    float* csig = (float*)(ws + WS_CSIG);

    hipLaunchKernelGGL(k_rowsq, dim3(NN / 256), dim3(256), 0, stream, x, sqv, dsum, nzc);
    hipLaunchKernelGGL(k_d2, dim3(GRID_D2), dim3(256), 0, stream, x, sqv, out, dsum, nzc);
    hipLaunchKernelGGL(k_sigmas, dim3(1), dim3(128), 0, stream, dsum, nzc, csig, KL, KK);
    hipLaunchKernelGGL(k_sweep_coarse, dim3(GRID_SW), dim3(256), 0, stream, out, lk, csig, KL, KK);
    hipLaunchKernelGGL(k_sweep_refine, dim3(GRID_SW), dim3(256), 0, stream, out, lk, csig, KL, KK);
    hipLaunchKernelGGL(k_final, dim3(2048), dim3(256), 0, stream, out, KL, KK, csig);
}